// Round 2
// baseline (616.330 us; speedup 1.0000x reference)
//
#include <hip/hip_runtime.h>
#include <stdint.h>

typedef __bf16 bf16;
typedef __bf16 bf16x8 __attribute__((ext_vector_type(8)));
typedef float f32x4 __attribute__((ext_vector_type(4)));

enum { EPI_STORE = 0, EPI_BIAS_RELU = 1, EPI_VRED = 2 };

// async global->LDS, 16 bytes per lane; LDS dest = wave-uniform base + lane*16
__device__ __forceinline__ void gload16(const bf16* g, bf16* l) {
  __builtin_amdgcn_global_load_lds(
      (const __attribute__((address_space(1))) unsigned int*)g,
      (__attribute__((address_space(3))) unsigned int*)l, 16, 0, 0);
}

// C[M,N] = A[M,K] @ B[K,N], B supplied transposed (Bt[N,K]). All operands bf16.
// Tile: BM=128 x BN=256 x BK=32, 256 threads = 4 waves, wave tile 64x128.
// T3+T4 pipeline: double-buffered LDS, global_load_lds prefetch of tile s+1
// issued before the wait for tile s; counted s_waitcnt vmcnt(6) + raw s_barrier
// (never vmcnt(0) in the main loop). Two barriers per step:
//   bar1: tile-s gloads landed everywhere -> safe to ds_read
//   bar2: all waves done ds_reading buf cur -> next step may overwrite it
// LDS bank-conflict fix (rule #21): linear LDS dest, XOR-swizzled GLOBAL source
// chunk (tid&3 ^ (tid>>3)&3), same XOR applied on the ds_read address.
// EPI_VRED: v[col] = sum_rows adj_row0[row] * relu(C[row][col] + bias[col])
template<int EPI>
__global__ __launch_bounds__(256, 2)
void gemm_bt(const bf16* __restrict__ Ap, const bf16* __restrict__ Btp,
             const float* __restrict__ bias, bf16* __restrict__ C,
             float* __restrict__ vpart, const float* __restrict__ adjp,
             int K, int ldA, int ldBt, int ldC,
             long sA, long sBt, long sC)
{
  constexpr int BM = 128, BN = 256, BK = 32;
  static_assert(BM / 64 + BN / 64 == 6, "vmcnt(6) assumes 6 gloads/thread/step");
  __shared__ __align__(16) bf16 As[2][BM * BK];   // 2 x 8 KB
  __shared__ __align__(16) bf16 Bs[2][BN * BK];   // 2 x 16 KB
  __shared__ float a0s[BM];
  __shared__ float vsum[BN];

  const int tid  = threadIdx.x;
  const int lane = tid & 63;
  const int wid  = tid >> 6;
  const int wm   = wid >> 1;   // 0..1 : m half (64 rows)
  const int wn   = wid & 1;    // 0..1 : n half (128 cols)
  const int l15  = lane & 15;
  const int quad = lane >> 4;

  const int nb = blockIdx.x, mb = blockIdx.y, g = blockIdx.z;

  const long aoff = (long)g * sA + (long)mb * BM * ldA;
  const long boff = (long)g * sBt + (long)nb * BN * ldBt;

  if constexpr (EPI == EPI_VRED) {
    if (tid < BM) a0s[tid] = adjp[(long)g * sA + mb * BM + tid];  // adj[g][0][row]
    vsum[tid] = 0.f;
  }

  // staging: thread tid fills LDS bytes [tid*16, tid*16+16) of each 64-row pass,
  // fetching the XOR-swizzled global k-chunk so reads can be conflict-free.
  const int r   = tid >> 2;                                  // row within pass
  const int kcs = (((tid & 3) ^ ((tid >> 3) & 3)) << 3);     // swizzled k-chunk (elems)

  const bf16* Ag0 = Ap + aoff;
  const bf16* Bg0 = Btp + boff;

  auto issueG = [&](int s, int buf) {
    const int k0 = s * BK;
    #pragma unroll
    for (int p = 0; p < BM / 64; ++p)
      gload16(Ag0 + (long)(p * 64 + r) * ldA + k0 + kcs, &As[buf][p * 2048 + tid * 8]);
    #pragma unroll
    for (int p = 0; p < BN / 64; ++p)
      gload16(Bg0 + (long)(p * 64 + r) * ldBt + k0 + kcs, &Bs[buf][p * 2048 + tid * 8]);
  };

  // read-side swizzle: LDS chunk position holding global chunk `quad` of row
  // (row>>1)&3 == (l15>>1)&3 since fragment row bases are multiples of 16
  const int csw = ((quad ^ ((l15 >> 1) & 3)) << 3);          // element offset in row

  f32x4 acc[4][8] = {};
  const int nsteps = K / BK;

  issueG(0, 0);
  int cur = 0;
  for (int s = 0; s < nsteps; ++s) {
    if (s + 1 < nsteps) {
      issueG(s + 1, cur ^ 1);                    // 6 gloads stay in flight
      asm volatile("s_waitcnt vmcnt(6)" ::: "memory");   // tile-s loads done
    } else {
      asm volatile("s_waitcnt vmcnt(0)" ::: "memory");
    }
    __builtin_amdgcn_s_barrier();                // tile s visible to all waves

    bf16x8 af[4], bfr[8];
    #pragma unroll
    for (int i = 0; i < 4; ++i)
      af[i] = *(const bf16x8*)&As[cur][(wm * 64 + i * 16 + l15) * BK + csw];
    #pragma unroll
    for (int j = 0; j < 8; ++j)
      bfr[j] = *(const bf16x8*)&Bs[cur][(wn * 128 + j * 16 + l15) * BK + csw];
    asm volatile("s_waitcnt lgkmcnt(0)" ::: "memory");     // my reads of cur done
    __builtin_amdgcn_s_barrier();                // everyone's reads done

    #pragma unroll
    for (int i = 0; i < 4; ++i)
      #pragma unroll
      for (int j = 0; j < 8; ++j)
        acc[i][j] = __builtin_amdgcn_mfma_f32_16x16x32_bf16(af[i], bfr[j], acc[i][j], 0, 0, 0);
    cur ^= 1;
  }

  if constexpr (EPI == EPI_STORE || EPI == EPI_BIAS_RELU) {
    bf16* Cg = C + (long)g * sC;
    #pragma unroll
    for (int i = 0; i < 4; ++i) {
      const int row0 = mb * BM + wm * 64 + i * 16 + quad * 4;
      #pragma unroll
      for (int j = 0; j < 8; ++j) {
        const int col = nb * BN + wn * 128 + j * 16 + l15;
        float bv = 0.f;
        if constexpr (EPI == EPI_BIAS_RELU) bv = bias[col];
        #pragma unroll
        for (int rr = 0; rr < 4; ++rr) {
          float v = acc[i][j][rr];
          if constexpr (EPI == EPI_BIAS_RELU) v = fmaxf(v + bv, 0.f);
          Cg[(long)(row0 + rr) * ldC + col] = (bf16)v;
        }
      }
    }
  } else {  // EPI_VRED: H2 never materialized
    __syncthreads();
    #pragma unroll
    for (int j = 0; j < 8; ++j) {
      const int col = wn * 128 + j * 16 + l15;
      const float bv = bias[col];
      float p = 0.f;
      #pragma unroll
      for (int i = 0; i < 4; ++i) {
        const int lr = wm * 64 + i * 16 + quad * 4;
        #pragma unroll
        for (int rr = 0; rr < 4; ++rr)
          p += fmaxf(acc[i][j][rr] + bv, 0.f) * a0s[lr + rr];
      }
      atomicAdd(&vsum[col], p);
    }
    __syncthreads();
    vpart[((long)g * 8 + mb) * 256 + tid] = vsum[tid];
  }
}

// Streaming f32 -> bf16 conversion for two arrays in one launch (8 elems/thread/iter)
__global__ void cvt2(const float* __restrict__ a, bf16* __restrict__ ao, long na8,
                     const float* __restrict__ b, bf16* __restrict__ bo, long nb8)
{
  const long stride = (long)gridDim.x * blockDim.x;
  for (long i = (long)blockIdx.x * blockDim.x + threadIdx.x; i < na8 + nb8; i += stride) {
    const float* src; bf16* dst; long k;
    if (i < na8) { src = a; dst = ao; k = i; } else { src = b; dst = bo; k = i - na8; }
    const float4* s = (const float4*)(src + k * 8);
    float4 v0 = s[0], v1 = s[1];
    bf16x8 w;
    w[0]=(bf16)v0.x; w[1]=(bf16)v0.y; w[2]=(bf16)v0.z; w[3]=(bf16)v0.w;
    w[4]=(bf16)v1.x; w[5]=(bf16)v1.y; w[6]=(bf16)v1.z; w[7]=(bf16)v1.w;
    *(bf16x8*)(dst + k * 8) = w;
  }
}

// Transpose + convert weights: W0t[h][k]=W0[k][h] (256x128), W1t[h][k]=W1[k][h] (256x256)
__global__ void prep_w(const float* __restrict__ W0, const float* __restrict__ W1,
                       bf16* __restrict__ W0t, bf16* __restrict__ W1t)
{
  const int idx = blockIdx.x * 256 + threadIdx.x;  // 0..65535
  if (idx < 256 * 128) {
    const int h = idx >> 7, k = idx & 127;
    W0t[idx] = (bf16)W0[k * 256 + h];
  }
  const int h = idx >> 8, k = idx & 255;
  W1t[idx] = (bf16)W1[k * 256 + h];
}

// Per graph: v = sum of 8 partials; h3 = relu(v@W2 + b2); out = h3@Wl + bl (all fp32)
__global__ void finish_k(const float* __restrict__ vpart, const float* __restrict__ W2,
                         const float* __restrict__ b2, const float* __restrict__ Wl,
                         const float* __restrict__ bl, float* __restrict__ out)
{
  const int b = blockIdx.x, t = threadIdx.x;
  __shared__ float v[256], h3[256];
  float s = 0.f;
  #pragma unroll
  for (int mb = 0; mb < 8; ++mb) s += vpart[((long)b * 8 + mb) * 256 + t];
  v[t] = s;
  __syncthreads();
  float z = b2[t];
  for (int k = 0; k < 256; ++k) z += v[k] * W2[k * 256 + t];
  h3[t] = fmaxf(z, 0.f);
  __syncthreads();
  if (t < 128) {
    float o = bl[t];
    for (int h = 0; h < 256; ++h) o += h3[h] * Wl[h * 128 + t];
    out[(long)b * 128 + t] = o;
  }
}

extern "C" void kernel_launch(void* const* d_in, const int* in_sizes, int n_in,
                              void* d_out, int out_size, void* d_ws, size_t ws_size,
                              hipStream_t stream) {
  const float* embs = (const float*)d_in[0];  // [64,1024,128]
  const float* adj  = (const float*)d_in[1];  // [64,1024,1024]
  const float* W0   = (const float*)d_in[2];  // [128,256]
  const float* b0   = (const float*)d_in[3];
  const float* W1   = (const float*)d_in[4];  // [256,256]
  const float* b1   = (const float*)d_in[5];
  const float* W2   = (const float*)d_in[6];  // [256,256]
  const float* b2   = (const float*)d_in[7];
  const float* Wl   = (const float*)d_in[8];  // [256,128]
  const float* bl   = (const float*)d_in[9];
  float* out = (float*)d_out;

  char* ws = (char*)d_ws;
  bf16*  Zt     = (bf16*)(ws);                 // [64][256][1024] bf16 (Z0t then Z1t)
  bf16*  Hb     = (bf16*)(ws + 33554432);      // [64][1024][256] bf16 (H1)
  bf16*  W0t    = (bf16*)(ws + 67108864);      // [256][128]
  bf16*  W1t    = (bf16*)(ws + 67174400);      // [256][256]
  float* vpart  = (float*)(ws + 67305472);     // [64][8][256] f32
  bf16*  embs16 = (bf16*)(ws + 67829760);      // [64][1024][128] bf16, 16 MB
  bf16*  adj16  = (bf16*)(ws + 134217728);     // [64][1024][1024] bf16, 128 MB
  // max offset used = 256 MiB; r1 PASS already proved ws >= 256 MiB

  prep_w<<<256, 256, 0, stream>>>(W0, W1, W0t, W1t);

  // one streaming pass: adj (268 MB f32 -> 134 MB bf16) + embs (33 -> 17 MB)
  cvt2<<<2048, 256, 0, stream>>>(adj, adj16, 64L * 1024 * 1024 / 8,
                                 embs, embs16, 64L * 1024 * 128 / 8);

  // L1: Z0t[h,n] = sum_k W0t[h,k]*embs16[n,k] : M=256,N=1024,K=128
  gemm_bt<EPI_STORE><<<dim3(4, 2, 64), 256, 0, stream>>>(
      W0t, embs16, nullptr, Zt, nullptr, nullptr,
      128, 128, 128, 1024, 0L, 131072L, 262144L);

  // L2: H1[n,h] = relu(sum_m adj16[n,m]*Z0t[h,m] + b0[h]) : M=1024,N=256,K=1024
  gemm_bt<EPI_BIAS_RELU><<<dim3(1, 8, 64), 256, 0, stream>>>(
      adj16, Zt, b0, Hb, nullptr, nullptr,
      1024, 1024, 1024, 256, 1048576L, 262144L, 262144L);

  // L3: Z1t[h,n] = sum_k W1t[h,k]*H1[n,k] : M=256,N=1024,K=256
  gemm_bt<EPI_STORE><<<dim3(4, 2, 64), 256, 0, stream>>>(
      W1t, Hb, nullptr, Zt, nullptr, nullptr,
      256, 256, 256, 1024, 0L, 262144L, 262144L);

  // L4: vpart[g,mb,h] = sum_{rows in mb} adj[g,0,row]*relu(adj16@Z1t + b1)[row,h]
  gemm_bt<EPI_VRED><<<dim3(1, 8, 64), 256, 0, stream>>>(
      adj16, Zt, b1, nullptr, vpart, adj,
      1024, 1024, 1024, 256, 1048576L, 262144L, 0L);

  finish_k<<<64, 256, 0, stream>>>(vpart, W2, b2, Wl, bl, out);
}

// Round 3
// 601.652 us; speedup vs baseline: 1.0244x; 1.0244x over previous
//
#include <hip/hip_runtime.h>
#include <stdint.h>

typedef __bf16 bf16;
typedef __bf16 bf16x8 __attribute__((ext_vector_type(8)));
typedef float f32x4 __attribute__((ext_vector_type(4)));

enum { EPI_STORE = 0, EPI_BIAS_RELU = 1, EPI_VRED = 2 };

// async global->LDS, 16 bytes per lane; LDS dest = wave-uniform base + lane*16
__device__ __forceinline__ void gload16(const bf16* g, bf16* l) {
  __builtin_amdgcn_global_load_lds(
      (const __attribute__((address_space(1))) unsigned int*)g,
      (__attribute__((address_space(3))) unsigned int*)l, 16, 0, 0);
}

// C[M,N] = A[M,K] @ B[K,N], B supplied transposed (Bt[N,K]).
// Tile: BM=128 x BN=256 x BK=32, 256 threads = 4 waves, wave tile 64x128.
// DEPTH-2 pipeline (T3+T4): triple-buffered LDS; tile s+2 issued at step s,
// waited (counted vmcnt, gloads only -- compiler tracks register loads) at s+2.
// Two barriers/step: bar1 = tile-s loads landed everywhere; bar2 = all waves
// done reading buf[s%3] (so step s+1 may overwrite buf[(s+3)%3]==buf[s%3]).
// LDS chunk swizzle (rule #21, both-sides): LDS[row][pos] holds global chunk
// pos ^ ((row>>1)&3); gload path swizzles the GLOBAL source, f32 path swizzles
// the ds_write position; reads use csw = quad ^ ((l15>>1)&3).
// A_F32: A streamed f32, reg-staged depth-2 (two named pf sets, 2x unrolled
// loop, n must be even), cvt->LDS commit fused; WRITE_A16 also stores the
// bf16 copy (unswizzled) so the next GEMM can read A as bf16.
// EPI_VRED: v[col] = sum_rows adj_row0[row] * relu(C[row][col] + bias[col])
template<bool A_F32, int EPI, bool WRITE_A16>
__global__ __launch_bounds__(256, 2)
void gemm_bt(const void* __restrict__ Ap, const bf16* __restrict__ Btp,
             const float* __restrict__ bias, bf16* __restrict__ C,
             float* __restrict__ vpart, const float* __restrict__ adjp,
             bf16* __restrict__ A16,
             int K, int ldA, int ldBt, int ldC,
             long sA, long sBt, long sC)
{
  constexpr int BM = 128, BN = 256, BK = 32;
  __shared__ __align__(16) bf16 As[3][BM * BK];   // 3 x 8 KB
  __shared__ __align__(16) bf16 Bs[3][BN * BK];   // 3 x 16 KB
  __shared__ float a0s[BM];
  __shared__ float vsum[BN];

  const int tid  = threadIdx.x;
  const int lane = tid & 63;
  const int wid  = tid >> 6;
  const int wm   = wid >> 1;   // 0..1 : m half (64 rows)
  const int wn   = wid & 1;    // 0..1 : n half (128 cols)
  const int l15  = lane & 15;
  const int quad = lane >> 4;

  const int nb = blockIdx.x, mb = blockIdx.y, g = blockIdx.z;

  const long aoff = (long)g * sA + (long)mb * BM * ldA;
  const long boff = (long)g * sBt + (long)nb * BN * ldBt;

  if constexpr (EPI == EPI_VRED) {
    if (tid < BM) a0s[tid] = adjp[(long)g * sA + mb * BM + tid];  // adj[g][0][row]
    vsum[tid] = 0.f;
  }

  // staging geometry: thread tid covers row r = tid>>2 (per 64-row pass),
  // 16-byte chunk index c4 = tid&3; swizzle key sw = (r>>1)&3.
  const int r   = tid >> 2;
  const int c4  = tid & 3;
  const int sw  = (r >> 1) & 3;
  const int kcs = (c4 ^ sw) << 3;   // swizzled chunk (elems): gload SOURCE / f32 ds_write POS
  const int kcp = c4 << 3;          // plain chunk: f32 global loads + A16 stores
  const int csw = (quad ^ ((l15 >> 1) & 3)) << 3;  // read-side chunk position

  const bf16* Bg0 = Btp + boff;

  auto issueB = [&](int s, int buf) {
    const bf16* Bg = Bg0 + s * BK;
    #pragma unroll
    for (int p = 0; p < 4; ++p)
      gload16(Bg + (long)(p * 64 + r) * ldBt + kcs, &Bs[buf][p * 2048 + tid * 8]);
  };
  auto issueAg = [&](int s, int buf) {
    const bf16* Ag = (const bf16*)Ap + aoff + s * BK;
    #pragma unroll
    for (int p = 0; p < 2; ++p)
      gload16(Ag + (long)(p * 64 + r) * ldA + kcs, &As[buf][p * 2048 + tid * 8]);
  };
  auto issueAf = [&](int s, float4 (&pf)[4]) {
    const float* Ag = (const float*)Ap + aoff + s * BK;
    #pragma unroll
    for (int p = 0; p < 2; ++p) {
      const float4* src = (const float4*)(Ag + (long)(p * 64 + r) * ldA + kcp);
      pf[p * 2 + 0] = src[0];
      pf[p * 2 + 1] = src[1];
    }
  };
  auto commitAf = [&](int s, float4 (&pf)[4], int buf) {
    #pragma unroll
    for (int p = 0; p < 2; ++p) {
      float4 v0 = pf[p * 2 + 0], v1 = pf[p * 2 + 1];
      bf16x8 w;
      w[0]=(bf16)v0.x; w[1]=(bf16)v0.y; w[2]=(bf16)v0.z; w[3]=(bf16)v0.w;
      w[4]=(bf16)v1.x; w[5]=(bf16)v1.y; w[6]=(bf16)v1.z; w[7]=(bf16)v1.w;
      *(bf16x8*)&As[buf][p * 2048 + r * 32 + kcs] = w;      // swizzled position
      if constexpr (WRITE_A16)
        *(bf16x8*)&A16[aoff + (long)(p * 64 + r) * ldA + s * BK + kcp] = w;
    }
  };

  f32x4 acc[4][8] = {};
  const int n = K / BK;

  if constexpr (!A_F32) {
    // ---------------- pure-bf16 path, depth-2 gload pipeline ----------------
    issueAg(0, 0); issueB(0, 0);
    if (n > 1) { issueAg(1, 1); issueB(1, 1); }
    for (int s = 0; s < n; ++s) {
      const int b = s % 3;
      if (s + 2 < n) { issueAg(s + 2, (s + 2) % 3); issueB(s + 2, (s + 2) % 3); }
      if (s + 2 < n)      asm volatile("s_waitcnt vmcnt(12)" ::: "memory");
      else if (s + 1 < n) asm volatile("s_waitcnt vmcnt(6)"  ::: "memory");
      else                asm volatile("s_waitcnt vmcnt(0)"  ::: "memory");
      __builtin_amdgcn_s_barrier();            // bar1: tile s landed everywhere

      bf16x8 af[4], bfr[8];
      #pragma unroll
      for (int i = 0; i < 4; ++i)
        af[i] = *(const bf16x8*)&As[b][(wm * 64 + i * 16 + l15) * 32 + csw];
      #pragma unroll
      for (int j = 0; j < 8; ++j)
        bfr[j] = *(const bf16x8*)&Bs[b][(wn * 128 + j * 16 + l15) * 32 + csw];
      asm volatile("s_waitcnt lgkmcnt(0)" ::: "memory");
      __builtin_amdgcn_s_barrier();            // bar2: everyone's reads done

      #pragma unroll
      for (int i = 0; i < 4; ++i)
        #pragma unroll
        for (int j = 0; j < 8; ++j)
          acc[i][j] = __builtin_amdgcn_mfma_f32_16x16x32_bf16(af[i], bfr[j], acc[i][j], 0, 0, 0);
    }
  } else {
    // ------------- f32-A path, depth-2 reg pipeline (n even) ---------------
    float4 pfa[4], pfb[4];
    issueAf(0, pfa); issueB(0, 0);
    issueAf(1, pfb); issueB(1, 1);
    commitAf(0, pfa, 0);                       // compiler auto-waits pfa loads
    asm volatile("s_waitcnt lgkmcnt(0)" ::: "memory");
    __builtin_amdgcn_s_barrier();

    auto bodyF = [&](int s, float4 (&pfI)[4], float4 (&pfC)[4]) {
      const int b = s % 3;
      if (s + 2 < n) { issueAf(s + 2, pfI); issueB(s + 2, (s + 2) % 3); }
      // counted waits cover the gloads only (8 tracked loads/step issue region)
      if (s + 2 < n)      asm volatile("s_waitcnt vmcnt(16)" ::: "memory");
      else if (s + 1 < n) asm volatile("s_waitcnt vmcnt(8)"  ::: "memory");
      else                asm volatile("s_waitcnt vmcnt(0)"  ::: "memory");
      __builtin_amdgcn_s_barrier();            // bar1

      bf16x8 af[4], bfr[8];
      #pragma unroll
      for (int i = 0; i < 4; ++i)
        af[i] = *(const bf16x8*)&As[b][(wm * 64 + i * 16 + l15) * 32 + csw];
      #pragma unroll
      for (int j = 0; j < 8; ++j)
        bfr[j] = *(const bf16x8*)&Bs[b][(wn * 128 + j * 16 + l15) * 32 + csw];
      if (s + 1 < n) commitAf(s + 1, pfC, (s + 1) % 3);   // cvt + ds_write + A16 store
      asm volatile("s_waitcnt lgkmcnt(0)" ::: "memory");
      __builtin_amdgcn_s_barrier();            // bar2 (commit visible for s+1)

      #pragma unroll
      for (int i = 0; i < 4; ++i)
        #pragma unroll
        for (int j = 0; j < 8; ++j)
          acc[i][j] = __builtin_amdgcn_mfma_f32_16x16x32_bf16(af[i], bfr[j], acc[i][j], 0, 0, 0);
    };
    for (int s = 0; s < n; s += 2) { bodyF(s, pfa, pfb); bodyF(s + 1, pfb, pfa); }
  }

  if constexpr (EPI == EPI_STORE || EPI == EPI_BIAS_RELU) {
    bf16* Cg = C + (long)g * sC;
    #pragma unroll
    for (int i = 0; i < 4; ++i) {
      const int row0 = mb * BM + wm * 64 + i * 16 + quad * 4;
      #pragma unroll
      for (int j = 0; j < 8; ++j) {
        const int col = nb * BN + wn * 128 + j * 16 + l15;
        float bv = 0.f;
        if constexpr (EPI == EPI_BIAS_RELU) bv = bias[col];
        #pragma unroll
        for (int rr = 0; rr < 4; ++rr) {
          float v = acc[i][j][rr];
          if constexpr (EPI == EPI_BIAS_RELU) v = fmaxf(v + bv, 0.f);
          Cg[(long)(row0 + rr) * ldC + col] = (bf16)v;
        }
      }
    }
  } else {  // EPI_VRED: H2 never materialized
    __syncthreads();
    #pragma unroll
    for (int j = 0; j < 8; ++j) {
      const int col = wn * 128 + j * 16 + l15;
      const float bv = bias[col];
      float p = 0.f;
      #pragma unroll
      for (int i = 0; i < 4; ++i) {
        const int lr = wm * 64 + i * 16 + quad * 4;
        #pragma unroll
        for (int rr = 0; rr < 4; ++rr)
          p += fmaxf(acc[i][j][rr] + bv, 0.f) * a0s[lr + rr];
      }
      atomicAdd(&vsum[col], p);
    }
    __syncthreads();
    vpart[((long)g * 8 + mb) * 256 + tid] = vsum[tid];
  }
}

// Streaming f32 -> bf16 conversion (8 elems/thread/iter)
__global__ void cvt1(const float* __restrict__ src, bf16* __restrict__ dst, long n8)
{
  const long stride = (long)gridDim.x * blockDim.x;
  for (long i = (long)blockIdx.x * blockDim.x + threadIdx.x; i < n8; i += stride) {
    const float4* s = (const float4*)(src + i * 8);
    float4 v0 = s[0], v1 = s[1];
    bf16x8 w;
    w[0]=(bf16)v0.x; w[1]=(bf16)v0.y; w[2]=(bf16)v0.z; w[3]=(bf16)v0.w;
    w[4]=(bf16)v1.x; w[5]=(bf16)v1.y; w[6]=(bf16)v1.z; w[7]=(bf16)v1.w;
    *(bf16x8*)(dst + i * 8) = w;
  }
}

// Transpose + convert weights: W0t[h][k]=W0[k][h] (256x128), W1t[h][k]=W1[k][h] (256x256)
__global__ void prep_w(const float* __restrict__ W0, const float* __restrict__ W1,
                       bf16* __restrict__ W0t, bf16* __restrict__ W1t)
{
  const int idx = blockIdx.x * 256 + threadIdx.x;  // 0..65535
  if (idx < 256 * 128) {
    const int h = idx >> 7, k = idx & 127;
    W0t[idx] = (bf16)W0[k * 256 + h];
  }
  const int h = idx >> 8, k = idx & 255;
  W1t[idx] = (bf16)W1[k * 256 + h];
}

// Per graph: v = sum of 8 partials; h3 = relu(v@W2 + b2); out = h3@Wl + bl (all fp32)
__global__ void finish_k(const float* __restrict__ vpart, const float* __restrict__ W2,
                         const float* __restrict__ b2, const float* __restrict__ Wl,
                         const float* __restrict__ bl, float* __restrict__ out)
{
  const int b = blockIdx.x, t = threadIdx.x;
  __shared__ float v[256], h3[256];
  float s = 0.f;
  #pragma unroll
  for (int mb = 0; mb < 8; ++mb) s += vpart[((long)b * 8 + mb) * 256 + t];
  v[t] = s;
  __syncthreads();
  float z = b2[t];
  for (int k = 0; k < 256; ++k) z += v[k] * W2[k * 256 + t];
  h3[t] = fmaxf(z, 0.f);
  __syncthreads();
  if (t < 128) {
    float o = bl[t];
    for (int h = 0; h < 256; ++h) o += h3[h] * Wl[h * 128 + t];
    out[(long)b * 128 + t] = o;
  }
}

extern "C" void kernel_launch(void* const* d_in, const int* in_sizes, int n_in,
                              void* d_out, int out_size, void* d_ws, size_t ws_size,
                              hipStream_t stream) {
  const float* embs = (const float*)d_in[0];  // [64,1024,128]
  const float* adj  = (const float*)d_in[1];  // [64,1024,1024]
  const float* W0   = (const float*)d_in[2];  // [128,256]
  const float* b0   = (const float*)d_in[3];
  const float* W1   = (const float*)d_in[4];  // [256,256]
  const float* b1   = (const float*)d_in[5];
  const float* W2   = (const float*)d_in[6];  // [256,256]
  const float* b2   = (const float*)d_in[7];
  const float* Wl   = (const float*)d_in[8];  // [256,128]
  const float* bl   = (const float*)d_in[9];
  float* out = (float*)d_out;

  char* ws = (char*)d_ws;
  bf16*  Zt     = (bf16*)(ws);                 // [64][256][1024] bf16 (Z0t then Z1t)
  bf16*  Hb     = (bf16*)(ws + 33554432);      // [64][1024][256] bf16 (H1)
  bf16*  W0t    = (bf16*)(ws + 67108864);      // [256][128]
  bf16*  W1t    = (bf16*)(ws + 67174400);      // [256][256]
  float* vpart  = (float*)(ws + 67305472);     // [64][8][256] f32
  bf16*  embs16 = (bf16*)(ws + 67829760);      // [64][1024][128] bf16, 16 MB
  bf16*  adj16  = (bf16*)(ws + 134217728);     // [64][1024][1024] bf16, 128 MB

  prep_w<<<256, 256, 0, stream>>>(W0, W1, W0t, W1t);
  cvt1<<<2048, 256, 0, stream>>>(embs, embs16, 64L * 1024 * 128 / 8);

  // L1: Z0t[h,n] = sum_k W0t[h,k]*embs16[n,k] : M=256,N=1024,K=128
  gemm_bt<false, EPI_STORE, false><<<dim3(4, 2, 64), 256, 0, stream>>>(
      W0t, embs16, nullptr, Zt, nullptr, nullptr, nullptr,
      128, 128, 128, 1024, 0L, 131072L, 262144L);

  // L2: H1[n,h] = relu(sum_m adj[n,m]*Z0t[h,m] + b0[h]) : M=1024,N=256,K=1024
  //     fused side-write of adj16 (each adj element staged exactly once: nb==1)
  gemm_bt<true, EPI_BIAS_RELU, true><<<dim3(1, 8, 64), 256, 0, stream>>>(
      adj, Zt, b0, Hb, nullptr, nullptr, adj16,
      1024, 1024, 1024, 256, 1048576L, 262144L, 262144L);

  // L3: Z1t[h,n] = sum_k W1t[h,k]*H1[n,k] : M=256,N=1024,K=256
  gemm_bt<false, EPI_STORE, false><<<dim3(4, 2, 64), 256, 0, stream>>>(
      W1t, Hb, nullptr, Zt, nullptr, nullptr, nullptr,
      256, 256, 256, 1024, 0L, 262144L, 262144L);

  // L4: vpart[g,mb,h] = sum_{rows in mb} adj[g,0,row]*relu(adj16@Z1t + b1)[row,h]
  gemm_bt<false, EPI_VRED, false><<<dim3(1, 8, 64), 256, 0, stream>>>(
      adj16, Zt, b1, nullptr, vpart, adj, nullptr,
      1024, 1024, 1024, 256, 1048576L, 262144L, 0L);

  finish_k<<<64, 256, 0, stream>>>(vpart, W2, b2, Wl, bl, out);
}

// Round 4
// 550.752 us; speedup vs baseline: 1.1191x; 1.0924x over previous
//
#include <hip/hip_runtime.h>
#include <stdint.h>

typedef __bf16 bf16;
typedef __bf16 bf16x8 __attribute__((ext_vector_type(8)));
typedef float f32x4 __attribute__((ext_vector_type(4)));

enum { EPI_STORE = 0, EPI_BIAS_RELU = 1, EPI_VRED = 2 };

// async global->LDS, 16 bytes per lane; LDS dest = wave-uniform base + lane*16
__device__ __forceinline__ void gload16(const bf16* g, bf16* l) {
  __builtin_amdgcn_global_load_lds(
      (const __attribute__((address_space(1))) unsigned int*)g,
      (__attribute__((address_space(3))) unsigned int*)l, 16, 0, 0);
}

// C[M,N] = A[M,K] @ B[K,N], B supplied transposed (Bt[N,K]).
// Tile: BM=128 x BN=256 x BK=32, 256 threads = 4 waves, wave tile 64x128.
// Depth-2 pipeline, triple-buffered LDS, counted vmcnt (never 0 mid-loop).
// K-STAGGER: each block starts its k-loop at a hashed rotation (wraps mod n)
// to de-phase the 512 lockstep blocks' HBM channel/bank access pattern.
// A_F32: A streamed f32 (nontemporal), reg-staged depth-2, cvt fused into
// the LDS commit. Requires n even.
// Epilogue (STORE/BIAS_RELU): per-wave LDS bounce -> dwordx4 C stores
// (replaces 128 scalar 2-byte stores/thread with 16 16-byte stores).
// EPI_VRED: v[col] = sum_rows adj_row0[row] * relu(C[row][col] + bias[col])
template<bool A_F32, int EPI>
__global__ __launch_bounds__(256, 2)
void gemm_bt(const void* __restrict__ Ap, const bf16* __restrict__ Btp,
             const float* __restrict__ bias, bf16* __restrict__ C,
             float* __restrict__ vpart, const float* __restrict__ adjp,
             int K, int ldA, int ldBt, int ldC,
             long sA, long sBt, long sC)
{
  constexpr int BM = 128, BN = 256, BK = 32;
  __shared__ __align__(16) char raw[73728];   // 3x(8K As + 16K Bs) = 72 KB
  auto Asb = [&](int b) -> bf16* { return (bf16*)(raw + b * 8192); };
  auto Bsb = [&](int b) -> bf16* { return (bf16*)(raw + 24576 + b * 16384); };
  __shared__ float a0s[BM];
  __shared__ float vsum[BN];

  const int tid  = threadIdx.x;
  const int lane = tid & 63;
  const int wid  = tid >> 6;
  const int wm   = wid >> 1;   // 0..1 : m half (64 rows)
  const int wn   = wid & 1;    // 0..1 : n half (128 cols)
  const int l15  = lane & 15;
  const int quad = lane >> 4;

  const int nb = blockIdx.x, mb = blockIdx.y, g = blockIdx.z;

  const long aoff = (long)g * sA + (long)mb * BM * ldA;
  const long boff = (long)g * sBt + (long)nb * BN * ldBt;

  if constexpr (EPI == EPI_VRED) {
    if (tid < BM) a0s[tid] = adjp[(long)g * sA + mb * BM + tid];  // adj[g][0][row]
    vsum[tid] = 0.f;
  }

  // staging geometry: thread covers row r (per 64-row pass), 16B chunk c4.
  const int r   = tid >> 2;
  const int c4  = tid & 3;
  const int sw  = (r >> 1) & 3;
  const int kcs = (c4 ^ sw) << 3;   // swizzled chunk: gload SOURCE / f32 ds_write POS
  const int kcp = c4 << 3;          // plain chunk: f32 global loads
  const int csw = (quad ^ ((l15 >> 1) & 3)) << 3;  // read-side chunk position

  const int n  = K / BK;            // power of two (4 / 8 / 32)
  const int nm = n - 1;
  const int off = (g * 11 + mb * 5 + nb * 3) & nm;      // per-block k rotation
  auto kof = [&](int s) { return ((s + off) & nm) * BK; };

  const bf16* Bg0 = Btp + boff;

  auto issueB = [&](int k0, int buf) {
    const bf16* Bg = Bg0 + k0;
    #pragma unroll
    for (int p = 0; p < 4; ++p)
      gload16(Bg + (long)(p * 64 + r) * ldBt + kcs, Bsb(buf) + p * 2048 + tid * 8);
  };
  auto issueAg = [&](int k0, int buf) {
    const bf16* Ag = (const bf16*)Ap + aoff + k0;
    #pragma unroll
    for (int p = 0; p < 2; ++p)
      gload16(Ag + (long)(p * 64 + r) * ldA + kcs, Asb(buf) + p * 2048 + tid * 8);
  };
  auto issueAf = [&](int k0, f32x4 (&pf)[4]) {
    const float* Ag = (const float*)Ap + aoff + k0;
    #pragma unroll
    for (int p = 0; p < 2; ++p) {
      const f32x4* src = (const f32x4*)(Ag + (long)(p * 64 + r) * ldA + kcp);
      pf[p * 2 + 0] = __builtin_nontemporal_load(src);      // adj: streamed once
      pf[p * 2 + 1] = __builtin_nontemporal_load(src + 1);
    }
  };
  auto commitAf = [&](f32x4 (&pf)[4], int buf) {
    #pragma unroll
    for (int p = 0; p < 2; ++p) {
      f32x4 v0 = pf[p * 2 + 0], v1 = pf[p * 2 + 1];
      bf16x8 w;
      w[0]=(bf16)v0[0]; w[1]=(bf16)v0[1]; w[2]=(bf16)v0[2]; w[3]=(bf16)v0[3];
      w[4]=(bf16)v1[0]; w[5]=(bf16)v1[1]; w[6]=(bf16)v1[2]; w[7]=(bf16)v1[3];
      *(bf16x8*)(Asb(buf) + p * 2048 + r * 32 + kcs) = w;   // swizzled position
    }
  };

  f32x4 acc[4][8] = {};

  if constexpr (!A_F32) {
    // ---------------- pure-bf16 path, depth-2 gload pipeline ----------------
    issueAg(kof(0), 0); issueB(kof(0), 0);
    if (n > 1) { issueAg(kof(1), 1); issueB(kof(1), 1); }
    for (int s = 0; s < n; ++s) {
      const int b = s % 3;
      if (s + 2 < n) { issueAg(kof(s + 2), (s + 2) % 3); issueB(kof(s + 2), (s + 2) % 3); }
      if (s + 2 < n)      asm volatile("s_waitcnt vmcnt(12)" ::: "memory");
      else if (s + 1 < n) asm volatile("s_waitcnt vmcnt(6)"  ::: "memory");
      else                asm volatile("s_waitcnt vmcnt(0)"  ::: "memory");
      __builtin_amdgcn_s_barrier();            // tile s landed everywhere

      bf16x8 af[4], bfr[8];
      #pragma unroll
      for (int i = 0; i < 4; ++i)
        af[i] = *(const bf16x8*)(Asb(b) + (wm * 64 + i * 16 + l15) * 32 + csw);
      #pragma unroll
      for (int j = 0; j < 8; ++j)
        bfr[j] = *(const bf16x8*)(Bsb(b) + (wn * 128 + j * 16 + l15) * 32 + csw);
      asm volatile("s_waitcnt lgkmcnt(0)" ::: "memory");
      __builtin_amdgcn_s_barrier();            // everyone's reads done

      #pragma unroll
      for (int i = 0; i < 4; ++i)
        #pragma unroll
        for (int j = 0; j < 8; ++j)
          acc[i][j] = __builtin_amdgcn_mfma_f32_16x16x32_bf16(af[i], bfr[j], acc[i][j], 0, 0, 0);
    }
  } else {
    // ------------- f32-A path, depth-2 reg pipeline (n even) ---------------
    f32x4 pfa[4], pfb[4];
    issueAf(kof(0), pfa); issueB(kof(0), 0);
    issueAf(kof(1), pfb); issueB(kof(1), 1);
    commitAf(pfa, 0);                          // compiler auto-waits pfa loads
    asm volatile("s_waitcnt vmcnt(8)" ::: "memory");   // drain tile-0 B gloads
    asm volatile("s_waitcnt lgkmcnt(0)" ::: "memory");
    __builtin_amdgcn_s_barrier();

    auto bodyF = [&](int s, f32x4 (&pfI)[4], f32x4 (&pfC)[4]) {
      const int b = s % 3;
      if (s + 2 < n) { issueAf(kof(s + 2), pfI); issueB(kof(s + 2), (s + 2) % 3); }
      if (s + 2 < n)      asm volatile("s_waitcnt vmcnt(16)" ::: "memory");
      else if (s + 1 < n) asm volatile("s_waitcnt vmcnt(8)"  ::: "memory");
      else                asm volatile("s_waitcnt vmcnt(0)"  ::: "memory");
      __builtin_amdgcn_s_barrier();            // tile s landed everywhere

      bf16x8 af[4], bfr[8];
      #pragma unroll
      for (int i = 0; i < 4; ++i)
        af[i] = *(const bf16x8*)(Asb(b) + (wm * 64 + i * 16 + l15) * 32 + csw);
      #pragma unroll
      for (int j = 0; j < 8; ++j)
        bfr[j] = *(const bf16x8*)(Bsb(b) + (wn * 128 + j * 16 + l15) * 32 + csw);
      if (s + 1 < n) commitAf(pfC, (s + 1) % 3);   // cvt + ds_write tile s+1
      asm volatile("s_waitcnt lgkmcnt(0)" ::: "memory");
      __builtin_amdgcn_s_barrier();            // reads done + commit visible

      #pragma unroll
      for (int i = 0; i < 4; ++i)
        #pragma unroll
        for (int j = 0; j < 8; ++j)
          acc[i][j] = __builtin_amdgcn_mfma_f32_16x16x32_bf16(af[i], bfr[j], acc[i][j], 0, 0, 0);
    };
    for (int s = 0; s < n; s += 2) { bodyF(s, pfa, pfb); bodyF(s + 1, pfb, pfa); }
  }

  if constexpr (EPI == EPI_STORE || EPI == EPI_BIAS_RELU) {
    // per-wave LDS bounce: scalar bf16 scatter -> LDS, then dwordx4 stores.
    constexpr int LDW = 140;                   // pad: quads hit disjoint banks
    bf16* slab = (bf16*)(raw + wid * 17920);   // [64][140] bf16, wave-private
    #pragma unroll
    for (int j = 0; j < 8; ++j) {
      float bv = 0.f;
      if constexpr (EPI == EPI_BIAS_RELU) bv = bias[nb * BN + wn * 128 + j * 16 + l15];
      #pragma unroll
      for (int i = 0; i < 4; ++i)
        #pragma unroll
        for (int rr = 0; rr < 4; ++rr) {
          float v = acc[i][j][rr];
          if constexpr (EPI == EPI_BIAS_RELU) v = fmaxf(v + bv, 0.f);
          slab[(i * 16 + quad * 4 + rr) * LDW + j * 16 + l15] = (bf16)v;
        }
    }
    asm volatile("s_waitcnt lgkmcnt(0)" ::: "memory");   // in-wave ds visibility
    bf16* Cg = C + (long)g * sC + (long)(mb * BM + wm * 64) * ldC + nb * BN + wn * 128;
    #pragma unroll
    for (int t = 0; t < 16; ++t) {
      const int rowl = t * 4 + quad;
      bf16x8 w = *(const bf16x8*)&slab[rowl * LDW + l15 * 8];
      *(bf16x8*)&Cg[(long)rowl * ldC + l15 * 8] = w;
    }
  } else {  // EPI_VRED: H2 never materialized
    __syncthreads();
    #pragma unroll
    for (int j = 0; j < 8; ++j) {
      const int col = wn * 128 + j * 16 + l15;
      const float bv = bias[col];
      float p = 0.f;
      #pragma unroll
      for (int i = 0; i < 4; ++i) {
        const int lr = wm * 64 + i * 16 + quad * 4;
        #pragma unroll
        for (int rr = 0; rr < 4; ++rr)
          p += fmaxf(acc[i][j][rr] + bv, 0.f) * a0s[lr + rr];
      }
      atomicAdd(&vsum[col], p);
    }
    __syncthreads();
    vpart[((long)g * 8 + mb) * 256 + tid] = vsum[tid];
  }
}

// Streaming f32 -> bf16 conversion (8 elems/thread/iter)
__global__ void cvt1(const float* __restrict__ src, bf16* __restrict__ dst, long n8)
{
  const long stride = (long)gridDim.x * blockDim.x;
  for (long i = (long)blockIdx.x * blockDim.x + threadIdx.x; i < n8; i += stride) {
    const f32x4* s = (const f32x4*)(src + i * 8);
    f32x4 v0 = s[0], v1 = s[1];
    bf16x8 w;
    w[0]=(bf16)v0[0]; w[1]=(bf16)v0[1]; w[2]=(bf16)v0[2]; w[3]=(bf16)v0[3];
    w[4]=(bf16)v1[0]; w[5]=(bf16)v1[1]; w[6]=(bf16)v1[2]; w[7]=(bf16)v1[3];
    *(bf16x8*)(dst + i * 8) = w;
  }
}

// Transpose + convert weights: W0t[h][k]=W0[k][h] (256x128), W1t[h][k]=W1[k][h] (256x256)
__global__ void prep_w(const float* __restrict__ W0, const float* __restrict__ W1,
                       bf16* __restrict__ W0t, bf16* __restrict__ W1t)
{
  const int idx = blockIdx.x * 256 + threadIdx.x;  // 0..65535
  if (idx < 256 * 128) {
    const int h = idx >> 7, k = idx & 127;
    W0t[idx] = (bf16)W0[k * 256 + h];
  }
  const int h = idx >> 8, k = idx & 255;
  W1t[idx] = (bf16)W1[k * 256 + h];
}

// Per graph: v = sum of 8 partials; h3 = relu(v@W2 + b2); out = h3@Wl + bl (all fp32)
__global__ void finish_k(const float* __restrict__ vpart, const float* __restrict__ W2,
                         const float* __restrict__ b2, const float* __restrict__ Wl,
                         const float* __restrict__ bl, float* __restrict__ out)
{
  const int b = blockIdx.x, t = threadIdx.x;
  __shared__ float v[256], h3[256];
  float s = 0.f;
  #pragma unroll
  for (int mb = 0; mb < 8; ++mb) s += vpart[((long)b * 8 + mb) * 256 + t];
  v[t] = s;
  __syncthreads();
  float z = b2[t];
  for (int k = 0; k < 256; ++k) z += v[k] * W2[k * 256 + t];
  h3[t] = fmaxf(z, 0.f);
  __syncthreads();
  if (t < 128) {
    float o = bl[t];
    for (int h = 0; h < 256; ++h) o += h3[h] * Wl[h * 128 + t];
    out[(long)b * 128 + t] = o;
  }
}

extern "C" void kernel_launch(void* const* d_in, const int* in_sizes, int n_in,
                              void* d_out, int out_size, void* d_ws, size_t ws_size,
                              hipStream_t stream) {
  const float* embs = (const float*)d_in[0];  // [64,1024,128]
  const float* adj  = (const float*)d_in[1];  // [64,1024,1024]
  const float* W0   = (const float*)d_in[2];  // [128,256]
  const float* b0   = (const float*)d_in[3];
  const float* W1   = (const float*)d_in[4];  // [256,256]
  const float* b1   = (const float*)d_in[5];
  const float* W2   = (const float*)d_in[6];  // [256,256]
  const float* b2   = (const float*)d_in[7];
  const float* Wl   = (const float*)d_in[8];  // [256,128]
  const float* bl   = (const float*)d_in[9];
  float* out = (float*)d_out;

  char* ws = (char*)d_ws;
  bf16*  Zt     = (bf16*)(ws);                 // [64][256][1024] bf16 (Z0t then Z1t)
  bf16*  Hb     = (bf16*)(ws + 33554432);      // [64][1024][256] bf16 (H1)
  bf16*  W0t    = (bf16*)(ws + 67108864);      // [256][128]
  bf16*  W1t    = (bf16*)(ws + 67174400);      // [256][256]
  float* vpart  = (float*)(ws + 67305472);     // [64][8][256] f32
  bf16*  embs16 = (bf16*)(ws + 67829760);      // [64][1024][128] bf16, 16 MB

  prep_w<<<256, 256, 0, stream>>>(W0, W1, W0t, W1t);
  cvt1<<<2048, 256, 0, stream>>>(embs, embs16, 64L * 1024 * 128 / 8);

  // L1: Z0t[h,n] = sum_k W0t[h,k]*embs16[n,k] : M=256,N=1024,K=128
  gemm_bt<false, EPI_STORE><<<dim3(4, 2, 64), 256, 0, stream>>>(
      W0t, embs16, nullptr, Zt, nullptr, nullptr,
      128, 128, 128, 1024, 0L, 131072L, 262144L);

  // L2: H1[n,h] = relu(sum_m adj[n,m]*Z0t[h,m] + b0[h]) : M=1024,N=256,K=1024
  gemm_bt<true, EPI_BIAS_RELU><<<dim3(1, 8, 64), 256, 0, stream>>>(
      adj, Zt, b0, Hb, nullptr, nullptr,
      1024, 1024, 1024, 256, 1048576L, 262144L, 262144L);

  // L3: Z1t[h,n] = sum_k W1t[h,k]*H1[n,k] : M=256,N=1024,K=256
  gemm_bt<false, EPI_STORE><<<dim3(4, 2, 64), 256, 0, stream>>>(
      W1t, Hb, nullptr, Zt, nullptr, nullptr,
      256, 256, 256, 1024, 0L, 262144L, 262144L);

  // L4: vpart[g,mb,h] = sum_{rows in mb} adj[g,0,row]*relu(adj@Z1t + b1)[row,h]
  gemm_bt<true, EPI_VRED><<<dim3(1, 8, 64), 256, 0, stream>>>(
      adj, Zt, b1, nullptr, vpart, adj,
      1024, 1024, 1024, 256, 1048576L, 262144L, 0L);

  finish_k<<<64, 256, 0, stream>>>(vpart, W2, b2, Wl, bl, out);
}